// Round 5
// baseline (547.120 us; speedup 1.0000x reference)
//
#include <hip/hip_runtime.h>
#include <hip/hip_bf16.h>

// CrossBandWindowAttentionWav — fully fused per-window kernel.
// B_=2048 windows, N=64 tok, C=384, 6 heads (qk d=16, v d=64), bias 225x6,
// mask (1024,64,64). prep: weights -> bf16 NxK + bias6 table. fused kernel:
// per block (1 window, 256 thr): q,k,v GEMMs (A-frags direct from global,
// B = weights from L2, zero staging LDS) -> LDS; attention (swapped-operand
// QK and PV, in-register softmax); att overlays LDS; proj GEMM -> fp32 out.
// HBM traffic = x + cx + mask + out only (~1.02 GB, 163 us floor).

typedef __attribute__((ext_vector_type(8))) short short8;
typedef __attribute__((ext_vector_type(4))) float f32x4;
typedef __attribute__((ext_vector_type(4))) unsigned short us4;

__device__ __forceinline__ f32x4 mfma_b16(short8 a, short8 b, f32x4 c) {
  return __builtin_amdgcn_mfma_f32_16x16x32_bf16(a, b, c, 0, 0, 0);
}

__device__ __forceinline__ unsigned short f2bf(float x) {
  unsigned u = __builtin_bit_cast(unsigned, x);
  u = (u + 0x7fffu + ((u >> 16) & 1u)) >> 16;  // RNE; inputs finite
  return (unsigned short)u;
}

__device__ __forceinline__ unsigned pack2(float a, float b) {
  return (unsigned)f2bf(a) | ((unsigned)f2bf(b) << 16);
}

// ---------------------------------------------------------------- prep ------
__global__ void prep_k(const float* __restrict__ Wq, const float* __restrict__ Wk,
                       const float* __restrict__ Wv, const float* __restrict__ Wp,
                       const float* __restrict__ rpb, const int* __restrict__ rpi,
                       const float* __restrict__ bk, const float* __restrict__ bv,
                       unsigned short* __restrict__ Wq_t, unsigned short* __restrict__ Wkv_t,
                       unsigned short* __restrict__ Wp_t, float* __restrict__ bias6,
                       float* __restrict__ bias_kv) {
  const int T0 = 96 * 384, T1 = 480 * 384, T2 = 384 * 384, T3 = 6 * 4096, T4 = 480;
  int total = T0 + T1 + T2 + T3 + T4;
  for (int i = blockIdx.x * blockDim.x + threadIdx.x; i < total;
       i += gridDim.x * blockDim.x) {
    int r = i;
    if (r < T0) {                       // Wq_t[n][k] = Wq[k][n]
      int n = r / 384, k = r % 384;
      Wq_t[r] = f2bf(Wq[k * 96 + n]);
    } else if ((r -= T0) < T1) {        // rows 0..95 = Wk^T, 96..479 = Wv^T
      int n = r / 384, k = r % 384;
      Wkv_t[r] = f2bf(n < 96 ? Wk[k * 96 + n] : Wv[k * 384 + (n - 96)]);
    } else if ((r -= T1) < T2) {
      int n = r / 384, k = r % 384;
      Wp_t[r] = f2bf(Wp[k * 384 + n]);
    } else if ((r -= T2) < T3) {        // bias6[h][i][j] = rpb[rpi[i][j]][h]
      int h = r >> 12, ij = r & 4095;
      bias6[r] = rpb[rpi[ij] * 6 + h];
    } else {
      r -= T3;
      bias_kv[r] = (r < 96) ? bk[r] : bv[r - 96];
    }
  }
}

// ------------------------------------------------- fused window kernel ------
// LDS map (80 KB): Q [64][96]bf16 swz @0 (12288) | K @12288 (12288) |
// P [64][64]bf16 swz @24576 (8192) | VT [384 d][64 tok]bf16 swz @32768 (49152).
// After attn barrier: ATT [64][384]bf16 swz overlays @0 (49152).
// Swizzle everywhere: byte ^= ((row&7)<<4).

// One 64-row x 96-col GEMM chunk, K=384. A: global fp32 (cvt in regs) or
// LDS bf16 (ATT). B: bf16 NxK weights from global (L2-hot). No LDS staging.
template <int MF, int ALDS>
__device__ __forceinline__ void chunk_gemm(const float* Ag, const char* Al,
                                           const unsigned short* Bt, int wm,
                                           int lr, int lg, f32x4 (&acc)[MF][6]) {
#pragma unroll
  for (int kk = 0; kk < 12; ++kk) {
    short8 af[MF];
#pragma unroll
    for (int mf = 0; mf < MF; ++mf) {
      const int row = wm + mf * 16 + lr;
      if (ALDS) {
        af[mf] = *reinterpret_cast<const short8*>(
            Al + ((row * 768 + kk * 64 + lg * 16) ^ ((row & 7) << 4)));
      } else {
        const float* p = Ag + (size_t)row * 384 + kk * 32 + lg * 8;
        const float4 v0 = *reinterpret_cast<const float4*>(p);
        const float4 v1 = *reinterpret_cast<const float4*>(p + 4);
        short8 t;
        t[0] = (short)f2bf(v0.x); t[1] = (short)f2bf(v0.y);
        t[2] = (short)f2bf(v0.z); t[3] = (short)f2bf(v0.w);
        t[4] = (short)f2bf(v1.x); t[5] = (short)f2bf(v1.y);
        t[6] = (short)f2bf(v1.z); t[7] = (short)f2bf(v1.w);
        af[mf] = t;
      }
    }
    short8 bf[6];
#pragma unroll
    for (int nf = 0; nf < 6; ++nf)
      bf[nf] = *reinterpret_cast<const short8*>(
          Bt + (size_t)(nf * 16 + lr) * 384 + kk * 32 + lg * 8);
#pragma unroll
    for (int mf = 0; mf < MF; ++mf)
#pragma unroll
      for (int nf = 0; nf < 6; ++nf)
        acc[mf][nf] = mfma_b16(af[mf], bf[nf], acc[mf][nf]);
  }
}

__global__ __launch_bounds__(256, 2) void fused_k(
    const float* __restrict__ x, const float* __restrict__ cx,
    const float* __restrict__ mask, const unsigned short* __restrict__ Wq_t,
    const unsigned short* __restrict__ Wkv_t, const unsigned short* __restrict__ Wp_t,
    const float* __restrict__ bq, const float* __restrict__ bkv,
    const float* __restrict__ bp, const float* __restrict__ bias6,
    float* __restrict__ out) {
  __shared__ char lds[81920];
  constexpr int QO = 0, KO = 12288, PO = 24576, VO = 32768;
  const int tid = threadIdx.x;
  const int lane = tid & 63, wid = tid >> 6;
  const int lr = lane & 15, lg = lane >> 4;
  const int w = blockIdx.x;
  const float* xw = x + (size_t)w * 24576;
  const float* cw = cx + (size_t)w * 24576;

  // ---- P0: q = x @ Wq^T + bq  -> Q_lds (wave: 16 rows x 96 cols)
  {
    f32x4 a1[1][6];
#pragma unroll
    for (int nf = 0; nf < 6; ++nf) a1[0][nf] = (f32x4){0.f, 0.f, 0.f, 0.f};
    chunk_gemm<1, 0>(xw, nullptr, Wq_t, wid * 16, lr, lg, a1);
#pragma unroll
    for (int nf = 0; nf < 6; ++nf) {
      const int col = nf * 16 + lr;
      const float bb = bq[col];
#pragma unroll
      for (int r = 0; r < 4; ++r) {
        const int row = wid * 16 + lg * 4 + r;
        *reinterpret_cast<unsigned short*>(
            lds + QO + ((row * 192 + col * 2) ^ ((row & 7) << 4))) =
            f2bf(a1[0][nf][r] + bb);
      }
    }
  }
  // ---- P1: k = cx @ Wk^T + bk  -> K_lds
  {
    f32x4 a1[1][6];
#pragma unroll
    for (int nf = 0; nf < 6; ++nf) a1[0][nf] = (f32x4){0.f, 0.f, 0.f, 0.f};
    chunk_gemm<1, 0>(cw, nullptr, Wkv_t, wid * 16, lr, lg, a1);
#pragma unroll
    for (int nf = 0; nf < 6; ++nf) {
      const int col = nf * 16 + lr;
      const float bb = bkv[col];
#pragma unroll
      for (int r = 0; r < 4; ++r) {
        const int row = wid * 16 + lg * 4 + r;
        *reinterpret_cast<unsigned short*>(
            lds + KO + ((row * 192 + col * 2) ^ ((row & 7) << 4))) =
            f2bf(a1[0][nf][r] + bb);
      }
    }
  }
  // ---- P2: v = cx @ Wv^T + bv  -> VT_lds transposed [d][tok]
  for (int c = 0; c < 2; ++c) {
    f32x4 a2[2][6];
#pragma unroll
    for (int mf = 0; mf < 2; ++mf)
#pragma unroll
      for (int nf = 0; nf < 6; ++nf) a2[mf][nf] = (f32x4){0.f, 0.f, 0.f, 0.f};
    const int colb = 96 + c * 192 + (wid & 1) * 96;   // Wkv row base
    chunk_gemm<2, 0>(cw, nullptr, Wkv_t + (size_t)colb * 384, (wid >> 1) * 32,
                     lr, lg, a2);
#pragma unroll
    for (int mf = 0; mf < 2; ++mf)
#pragma unroll
      for (int nf = 0; nf < 6; ++nf) {
        const int d = colb - 96 + nf * 16 + lr;       // 0..383
        const int tok0 = (wid >> 1) * 32 + mf * 16 + lg * 4;
        const float bb = bkv[96 + d];
        us4 pk = {f2bf(a2[mf][nf][0] + bb), f2bf(a2[mf][nf][1] + bb),
                  f2bf(a2[mf][nf][2] + bb), f2bf(a2[mf][nf][3] + bb)};
        *reinterpret_cast<us4*>(
            lds + VO + ((d * 128 + tok0 * 2) ^ ((d & 7) << 4))) = pk;
      }
  }
  __syncthreads();

  // ---- P3: attention. Each lane owns query row iq; 6 heads, wave-local.
  unsigned stash[48];
  const float* mw = mask + (size_t)(w & 1023) * 4096;
  const int iq = wid * 16 + lr;
#pragma unroll
  for (int h = 0; h < 6; ++h) {
    // S^T via mfma(K, Q): lane holds s[j = tj*16+lg*4+r] for row iq
    short8 qa = {0, 0, 0, 0, 0, 0, 0, 0};
    if (lg < 2)
      qa = *reinterpret_cast<const short8*>(
          lds + QO + ((iq * 192 + h * 32 + lg * 16) ^ ((iq & 7) << 4)));
    float sv[4][4];
#pragma unroll
    for (int tj = 0; tj < 4; ++tj) {
      short8 kf = {0, 0, 0, 0, 0, 0, 0, 0};
      const int jr = tj * 16 + lr;
      if (lg < 2)
        kf = *reinterpret_cast<const short8*>(
            lds + KO + ((jr * 192 + h * 32 + lg * 16) ^ ((jr & 7) << 4)));
      f32x4 z = {0.f, 0.f, 0.f, 0.f};
      f32x4 s = mfma_b16(kf, qa, z);
      const int j0 = tj * 16 + lg * 4;
      const float4 bi = *reinterpret_cast<const float4*>(bias6 + h * 4096 + iq * 64 + j0);
      const float4 mk = *reinterpret_cast<const float4*>(mw + iq * 64 + j0);
      sv[tj][0] = s[0] * 0.25f + bi.x + mk.x;
      sv[tj][1] = s[1] * 0.25f + bi.y + mk.y;
      sv[tj][2] = s[2] * 0.25f + bi.z + mk.z;
      sv[tj][3] = s[3] * 0.25f + bi.w + mk.w;
    }
    // row softmax: 16 in-lane + lanes iq±(16,32) hold the other quarters
    float mx = sv[0][0];
#pragma unroll
    for (int tj = 0; tj < 4; ++tj)
#pragma unroll
      for (int r = 0; r < 4; ++r) mx = fmaxf(mx, sv[tj][r]);
    mx = fmaxf(mx, __shfl_xor(mx, 16));
    mx = fmaxf(mx, __shfl_xor(mx, 32));
    float sum = 0.f;
#pragma unroll
    for (int tj = 0; tj < 4; ++tj)
#pragma unroll
      for (int r = 0; r < 4; ++r) {
        sv[tj][r] = __expf(sv[tj][r] - mx);
        sum += sv[tj][r];
      }
    sum += __shfl_xor(sum, 16);
    sum += __shfl_xor(sum, 32);
    const float inv = 1.0f / sum;
    // P[iq][j] bf16, packed 4-wide
#pragma unroll
    for (int tj = 0; tj < 4; ++tj) {
      us4 pk = {f2bf(sv[tj][0] * inv), f2bf(sv[tj][1] * inv),
                f2bf(sv[tj][2] * inv), f2bf(sv[tj][3] * inv)};
      *reinterpret_cast<us4*>(
          lds + PO + ((iq * 128 + (tj * 16 + lg * 4) * 2) ^ ((iq & 7) << 4))) = pk;
    }
    // PV via mfma(VT, P): lane holds att[iq][c = h*64+td*16+lg*4+r]
    short8 pa[2];
#pragma unroll
    for (int ks = 0; ks < 2; ++ks)
      pa[ks] = *reinterpret_cast<const short8*>(
          lds + PO + ((iq * 128 + ks * 64 + lg * 16) ^ ((iq & 7) << 4)));
#pragma unroll
    for (int td = 0; td < 4; ++td) {
      f32x4 o = {0.f, 0.f, 0.f, 0.f};
#pragma unroll
      for (int ks = 0; ks < 2; ++ks) {
        const int d = h * 64 + td * 16 + lr;
        short8 vb = *reinterpret_cast<const short8*>(
            lds + VO + ((d * 128 + ks * 64 + lg * 16) ^ ((d & 7) << 4)));
        o = mfma_b16(vb, pa[ks], o);
      }
      stash[h * 8 + td * 2 + 0] = pack2(o[0], o[1]);
      stash[h * 8 + td * 2 + 1] = pack2(o[2], o[3]);
    }
  }
  __syncthreads();  // all P3 reads done; ATT overlays Q/K/P/VT[0:16K)

  // spill att stash -> ATT_lds [tok][384] bf16 swz
#pragma unroll
  for (int h = 0; h < 6; ++h)
#pragma unroll
    for (int td = 0; td < 4; ++td)
#pragma unroll
      for (int p2 = 0; p2 < 2; ++p2) {
        const int c0 = h * 64 + td * 16 + lg * 4 + p2 * 2;
        *reinterpret_cast<unsigned*>(
            lds + ((iq * 768 + c0 * 2) ^ ((iq & 7) << 4))) =
            stash[h * 8 + td * 2 + p2];
      }
  __syncthreads();

  // ---- P4: out = att @ Wp^T + bp (fp32, direct global stores)
  for (int c = 0; c < 2; ++c) {
    f32x4 a2[2][6];
#pragma unroll
    for (int mf = 0; mf < 2; ++mf)
#pragma unroll
      for (int nf = 0; nf < 6; ++nf) a2[mf][nf] = (f32x4){0.f, 0.f, 0.f, 0.f};
    const int colb = c * 192 + (wid & 1) * 96;
    chunk_gemm<2, 1>(nullptr, lds, Wp_t + (size_t)colb * 384, (wid >> 1) * 32,
                     lr, lg, a2);
#pragma unroll
    for (int mf = 0; mf < 2; ++mf)
#pragma unroll
      for (int nf = 0; nf < 6; ++nf) {
        const int col = colb + nf * 16 + lr;
        const float bb = bp[col];
#pragma unroll
        for (int r = 0; r < 4; ++r) {
          const int tok = (wid >> 1) * 32 + mf * 16 + lg * 4 + r;
          out[(size_t)(w * 64 + tok) * 384 + col] = a2[mf][nf][r] + bb;
        }
      }
  }
}

// -------------------------------------------------------------- launch ------
extern "C" void kernel_launch(void* const* d_in, const int* in_sizes, int n_in,
                              void* d_out, int out_size, void* d_ws, size_t ws_size,
                              hipStream_t stream) {
  const float* x    = (const float*)d_in[0];
  const float* cx   = (const float*)d_in[1];
  const int*   rpi  = (const int*)d_in[2];
  const float* mask = (const float*)d_in[3];
  const float* Wq   = (const float*)d_in[4];
  const float* bq   = (const float*)d_in[5];
  const float* Wk   = (const float*)d_in[6];
  const float* bk   = (const float*)d_in[7];
  const float* Wv   = (const float*)d_in[8];
  const float* bv   = (const float*)d_in[9];
  const float* Wp   = (const float*)d_in[10];
  const float* bp   = (const float*)d_in[11];
  const float* rpb  = (const float*)d_in[12];

  char* ws = (char*)d_ws;
  unsigned short* Wq_t   = (unsigned short*)(ws + 0);        //  73,728 B
  unsigned short* Wkv_t  = (unsigned short*)(ws + 73728);    // 368,640 B
  unsigned short* Wp_t   = (unsigned short*)(ws + 442368);   // 294,912 B
  float*          bias6  = (float*)(ws + 737280);            //  98,304 B
  float*          biaskv = (float*)(ws + 835584);            //   1,920 B

  prep_k<<<256, 256, 0, stream>>>(Wq, Wk, Wv, Wp, rpb, rpi, bk, bv,
                                  Wq_t, Wkv_t, Wp_t, bias6, biaskv);
  fused_k<<<2048, 256, 0, stream>>>(x, cx, mask, Wq_t, Wkv_t, Wp_t,
                                    bq, biaskv, bp, bias6, (float*)d_out);
}

// Round 6
// 401.541 us; speedup vs baseline: 1.3626x; 1.3626x over previous
//
#include <hip/hip_runtime.h>
#include <hip/hip_bf16.h>

// CrossBandWindowAttentionWav. Pipeline: prep -> GEMM q -> GEMM k|v (v stored
// transposed per window) -> fused window attention -> GEMM proj (fp32 out).
// R6 GEMM: BM=64/BN=96/BK=64, 4 waves, 40KB LDS dbuf (4 blocks/CU),
// T3-minimum 2-phase schedule, global_load_lds w=16 for bf16 operands with
// pre-swizzled source (2-way-free LDS reads), reg-staged fp32 A (cvt_pk),
// XCD-aware bijective block swizzle, coalesced LDS-staged epilogues.

typedef __attribute__((ext_vector_type(8))) short short8;
typedef __attribute__((ext_vector_type(4))) float f32x4;

__device__ __forceinline__ f32x4 mfma_b16(short8 a, short8 b, f32x4 c) {
  return __builtin_amdgcn_mfma_f32_16x16x32_bf16(a, b, c, 0, 0, 0);
}

__device__ __forceinline__ unsigned short f2bf(float x) {
  unsigned u = __builtin_bit_cast(unsigned, x);
  u = (u + 0x7fffu + ((u >> 16) & 1u)) >> 16;  // RNE; inputs finite
  return (unsigned short)u;
}

__device__ __forceinline__ unsigned pack2(float a, float b) {
  return (unsigned)f2bf(a) | ((unsigned)f2bf(b) << 16);  // -> 2 bf16
}

// async global->LDS, 16B per lane; LDS base must be wave-uniform.
__device__ __forceinline__ void gl_lds16(const char* g, char* l) {
  __builtin_amdgcn_global_load_lds(
      (const __attribute__((address_space(1))) unsigned int*)g,
      (__attribute__((address_space(3))) unsigned int*)l, 16, 0, 0);
}

// ---------------------------------------------------------------- prep ------
__global__ void prep_k(const float* __restrict__ Wq, const float* __restrict__ Wk,
                       const float* __restrict__ Wv, const float* __restrict__ Wp,
                       const float* __restrict__ rpb, const int* __restrict__ rpi,
                       const float* __restrict__ bk, const float* __restrict__ bv,
                       unsigned short* __restrict__ Wq_t, unsigned short* __restrict__ Wkv_t,
                       unsigned short* __restrict__ Wp_t, float* __restrict__ bias6,
                       float* __restrict__ bias_kv) {
  const int T0 = 96 * 384, T1 = 480 * 384, T2 = 384 * 384, T3 = 6 * 4096, T4 = 480;
  int total = T0 + T1 + T2 + T3 + T4;
  for (int i = blockIdx.x * blockDim.x + threadIdx.x; i < total;
       i += gridDim.x * blockDim.x) {
    int r = i;
    if (r < T0) {                       // Wq_t[n][k] = Wq[k][n]
      int n = r / 384, k = r % 384;
      Wq_t[r] = f2bf(Wq[k * 96 + n]);
    } else if ((r -= T0) < T1) {        // rows 0..95 = Wk^T, 96..479 = Wv^T
      int n = r / 384, k = r % 384;
      Wkv_t[r] = f2bf(n < 96 ? Wk[k * 96 + n] : Wv[k * 384 + (n - 96)]);
    } else if ((r -= T1) < T2) {
      int n = r / 384, k = r % 384;
      Wp_t[r] = f2bf(Wp[k * 384 + n]);
    } else if ((r -= T2) < T3) {        // bias6[h][i][j] = rpb[rpi[i][j]][h]
      int h = r >> 12, ij = r & 4095;
      bias6[r] = rpb[rpi[ij] * 6 + h];
    } else {
      r -= T3;
      bias_kv[r] = (r < 96) ? bk[r] : bv[r - 96];
    }
  }
}

// ---------------------------------------------------------------- GEMM ------
// C[M=131072, N=NX*96] = A[M,384] @ Bt[N,384]^T + bias.  BM=64 BN=96 BK=64.
// grid = NX*2048, XCD-bijective swizzle. Rows in LDS are 128B = 8 16B-chunks,
// chunk c stored at c ^ (row&7)  (pre-swizzled global source for gl_lds paths).
// A_MODE 0: A fp32, reg-staged + cvt_pk.  1: A bf16 via global_load_lds.
// OUT_MODE 0: bf16 [M,96] | 1: fp32 [M,384] direct | 2: nx==0 -> k_out[M,96],
//             nx>=1 -> vt_out bf16 (win, d, tok) via LDS transpose.
template <int A_MODE, int OUT_MODE, int NX>
__global__ __launch_bounds__(256, 4) void gemm3_k(
    const void* __restrict__ Av, const unsigned short* __restrict__ Bt,
    const float* __restrict__ bias, void* __restrict__ Outv,
    unsigned short* __restrict__ k_out, unsigned short* __restrict__ vt_out) {
  __shared__ char lds[40960];  // A: 2x8KB @0, B: 2x12KB @16384
  constexpr int AB[2] = {0, 8192}, BB[2] = {16384, 28672};
  const int tid = threadIdx.x, lane = tid & 63, wid = tid >> 6;
  const int g = blockIdx.x;
  const int lg_id = (g & 7) * (NX * 256) + (g >> 3);
  const int my = lg_id / NX, nx = lg_id - my * NX;
  const int m0 = my * 64, n0 = nx * 96;
  const int wm = (wid >> 1) * 32, wn = (wid & 1) * 48;
  const int lr = lane & 15, lg = lane >> 4;

  float4 areg[4];
  const int ar = tid >> 2, aq = tid & 3;  // fp32-A staging: row, quarter

  auto a_issue_f32 = [&](int kt) {
    const float* A = (const float*)Av + (size_t)(m0 + ar) * 384 + kt * 64 + aq * 16;
#pragma unroll
    for (int p = 0; p < 4; ++p) areg[p] = *reinterpret_cast<const float4*>(A + p * 4);
  };
  auto a_write_f32 = [&](char* Ab) {
    unsigned pk[8];
#pragma unroll
    for (int p = 0; p < 4; ++p) {
      pk[p * 2]     = pack2(areg[p].x, areg[p].y);
      pk[p * 2 + 1] = pack2(areg[p].z, areg[p].w);
    }
    const int c0 = aq * 2;
    *reinterpret_cast<uint4*>(Ab + ar * 128 + ((c0 ^ (ar & 7)) * 16)) =
        make_uint4(pk[0], pk[1], pk[2], pk[3]);
    *reinterpret_cast<uint4*>(Ab + ar * 128 + (((c0 + 1) ^ (ar & 7)) * 16)) =
        make_uint4(pk[4], pk[5], pk[6], pk[7]);
  };
  auto a_issue_lds = [&](int kt, char* Ab) {
    const char* Ag = (const char*)Av;
#pragma unroll
    for (int j = 0; j < 2; ++j) {
      const int rb = (wid * 2 + j) * 8;
      const int row = rb + (lane >> 3), c = lane & 7;
      gl_lds16(Ag + (size_t)(m0 + row) * 768 + kt * 128 + ((c ^ (row & 7)) * 16),
               Ab + rb * 128);
    }
  };
  auto b_issue = [&](int kt, char* Bb) {
#pragma unroll
    for (int j = 0; j < 3; ++j) {
      const int rb = (wid * 3 + j) * 8;
      const int row = rb + (lane >> 3), c = lane & 7;
      gl_lds16((const char*)Bt + (size_t)(n0 + row) * 768 + kt * 128 +
                   ((c ^ (row & 7)) * 16),
               Bb + rb * 128);
    }
  };

  f32x4 acc[2][3];
#pragma unroll
  for (int i = 0; i < 2; ++i)
#pragma unroll
    for (int j = 0; j < 3; ++j) acc[i][j] = (f32x4){0.f, 0.f, 0.f, 0.f};

  // prologue
  if (A_MODE == 0) { a_issue_f32(0); a_write_f32(lds + AB[0]); }
  else a_issue_lds(0, lds + AB[0]);
  b_issue(0, lds + BB[0]);
  __syncthreads();

  int cur = 0;
  for (int kt = 0; kt < 6; ++kt) {
    char* An = lds + AB[cur ^ 1];
    char* Bn = lds + BB[cur ^ 1];
    if (kt < 5) {  // issue next-tile loads; they land during compute
      if (A_MODE == 0) a_issue_f32(kt + 1);
      else a_issue_lds(kt + 1, An);
      b_issue(kt + 1, Bn);
    }
    {
      const char* Ab = lds + AB[cur];
      const char* Bb = lds + BB[cur];
#pragma unroll
      for (int ks = 0; ks < 2; ++ks) {
        short8 a[2], b[3];
#pragma unroll
        for (int mf = 0; mf < 2; ++mf) {
          const int row = wm + mf * 16 + lr;
          a[mf] = *reinterpret_cast<const short8*>(
              Ab + row * 128 + (((ks * 4 + lg) ^ (row & 7)) * 16));
        }
#pragma unroll
        for (int nf = 0; nf < 3; ++nf) {
          const int row = wn + nf * 16 + lr;
          b[nf] = *reinterpret_cast<const short8*>(
              Bb + row * 128 + (((ks * 4 + lg) ^ (row & 7)) * 16));
        }
#pragma unroll
        for (int mf = 0; mf < 2; ++mf)
#pragma unroll
          for (int nf = 0; nf < 3; ++nf)
            acc[mf][nf] = mfma_b16(a[mf], b[nf], acc[mf][nf]);
      }
    }
    if (kt < 5 && A_MODE == 0) a_write_f32(An);  // waits areg, cvt, ds_write
    __syncthreads();  // drains vmcnt (gl_lds) + lgkm -> next buffer ready
    cur ^= 1;
  }

  // ---- epilogues (LDS free for reuse after final barrier)
  if (OUT_MODE == 0 || (OUT_MODE == 2 && nx == 0)) {  // bf16 [M,96], ld 208 pad
    unsigned short* dst = (OUT_MODE == 0) ? (unsigned short*)Outv : k_out;
#pragma unroll
    for (int mf = 0; mf < 2; ++mf)
#pragma unroll
      for (int nf = 0; nf < 3; ++nf) {
        const int col = wn + nf * 16 + lr;
        const float bb = bias[col];
#pragma unroll
        for (int r = 0; r < 4; ++r) {
          const int row = wm + mf * 16 + lg * 4 + r;
          *reinterpret_cast<unsigned short*>(lds + row * 208 + col * 2) =
              f2bf(acc[mf][nf][r] + bb);
        }
      }
    __syncthreads();
#pragma unroll
    for (int j = 0; j < 3; ++j) {
      const int Lb = (j * 256 + tid) * 16;
      const int row = Lb / 192, inner = Lb % 192;
      *reinterpret_cast<uint4*>((char*)dst + (size_t)(m0 + row) * 192 + inner) =
          *reinterpret_cast<const uint4*>(lds + row * 208 + inner);
    }
  } else if (OUT_MODE == 1) {  // fp32 [M,384] direct
    float* outp = (float*)Outv;
#pragma unroll
    for (int mf = 0; mf < 2; ++mf)
#pragma unroll
      for (int nf = 0; nf < 3; ++nf) {
        const int col = n0 + wn + nf * 16 + lr;
        const float bb = bias[col];
#pragma unroll
        for (int r = 0; r < 4; ++r) {
          const int row = m0 + wm + mf * 16 + lg * 4 + r;
          outp[(size_t)row * 384 + col] = acc[mf][nf][r] + bb;
        }
      }
  } else {  // vt: transpose to (win=my, d, tok) via LDS [96][144-pad]
#pragma unroll
    for (int mf = 0; mf < 2; ++mf)
#pragma unroll
      for (int nf = 0; nf < 3; ++nf) {
        const int dl = wn + nf * 16 + lr;
        const float bb = bias[n0 + dl];
        const int tok0 = wm + mf * 16 + lg * 4;
        *reinterpret_cast<unsigned*>(lds + dl * 144 + tok0 * 2) =
            pack2(acc[mf][nf][0] + bb, acc[mf][nf][1] + bb);
        *reinterpret_cast<unsigned*>(lds + dl * 144 + tok0 * 2 + 4) =
            pack2(acc[mf][nf][2] + bb, acc[mf][nf][3] + bb);
      }
    __syncthreads();
#pragma unroll
    for (int j = 0; j < 3; ++j) {
      const int Lc = j * 256 + tid;  // 16B chunk id, 768 total
      const int dl = Lc >> 3, c = Lc & 7;
      *reinterpret_cast<uint4*>((char*)vt_out + (size_t)my * 49152 +
                                (size_t)((nx - 1) * 96 + dl) * 128 + c * 16) =
          *reinterpret_cast<const uint4*>(lds + dl * 144 + c * 16);
    }
  }
}

// ----------------------------------------------------------- attention ------
// 1 block = 1 window. 4 waves; wave = one 16-row query tile (ti=wid).
__global__ __launch_bounds__(256) void attn_k(
    const unsigned short* __restrict__ q_buf, const unsigned short* __restrict__ k_buf,
    const unsigned short* __restrict__ vt_buf, const float* __restrict__ bias6,
    const float* __restrict__ mask, unsigned short* __restrict__ att_out) {
  __shared__ unsigned short vt_lds[384 * 64];  // [d][tok], 128B rows, swizzled
  __shared__ float S[64 * 68];
  __shared__ unsigned short P[64 * 64];        // 128B rows, swizzled
  const int w = blockIdx.x;
  const int tid = threadIdx.x;
  const int lane = tid & 63, wid = tid >> 6;

  const unsigned short* vsrc = vt_buf + (size_t)w * 24576;
#pragma unroll
  for (int p = 0; p < 12; ++p) {
    int e = (p * 256 + tid) * 8;
    int d = e >> 6, j = e & 63;
    const float4 v = *reinterpret_cast<const float4*>(vsrc + e);
    *reinterpret_cast<float4*>((char*)vt_lds + ((d * 128 + j * 2) ^ ((d & 7) << 4))) = v;
  }
  __syncthreads();

  const float* maskw = mask + (size_t)(w & 1023) * 4096;
  const int ti = wid;
  const int lr = lane & 15, lg = lane >> 4;
  const int srow = tid >> 2, sq = tid & 3;  // softmax: 4 lanes per row

  for (int h = 0; h < 6; ++h) {
    short8 afrag = {0, 0, 0, 0, 0, 0, 0, 0};
    if (lg < 2)
      afrag = *reinterpret_cast<const short8*>(
          q_buf + (size_t)(w * 64 + ti * 16 + lr) * 96 + h * 16 + lg * 8);
#pragma unroll
    for (int tj = 0; tj < 4; ++tj) {
      short8 bfrag = {0, 0, 0, 0, 0, 0, 0, 0};
      if (lg < 2)
        bfrag = *reinterpret_cast<const short8*>(
            k_buf + (size_t)(w * 64 + tj * 16 + lr) * 96 + h * 16 + lg * 8);
      f32x4 zero = {0.f, 0.f, 0.f, 0.f};
      f32x4 s = mfma_b16(afrag, bfrag, zero);
#pragma unroll
      for (int r = 0; r < 4; ++r) {
        int i = ti * 16 + lg * 4 + r;
        int j = tj * 16 + lr;
        S[i * 68 + j] = s[r] * 0.25f + bias6[h * 4096 + i * 64 + j] + maskw[i * 64 + j];
      }
    }
    float buf[16];
    float mx = -3.0e38f;
#pragma unroll
    for (int c = 0; c < 16; ++c) {
      buf[c] = S[srow * 68 + sq * 16 + c];
      mx = fmaxf(mx, buf[c]);
    }
    mx = fmaxf(mx, __shfl_xor(mx, 1));
    mx = fmaxf(mx, __shfl_xor(mx, 2));
    float sum = 0.f;
#pragma unroll
    for (int c = 0; c < 16; ++c) {
      buf[c] = __expf(buf[c] - mx);
      sum += buf[c];
    }
    sum += __shfl_xor(sum, 1);
    sum += __shfl_xor(sum, 2);
    float inv = 1.0f / sum;
#pragma unroll
    for (int c = 0; c < 16; c += 2) {
      unsigned pk = pack2(buf[c] * inv, buf[c + 1] * inv);
      *reinterpret_cast<unsigned*>(
          (char*)P + ((srow * 128 + (sq * 16 + c) * 2) ^ ((srow & 7) << 4))) = pk;
    }
    short8 pa[2];
#pragma unroll
    for (int ks = 0; ks < 2; ++ks) {
      int i = ti * 16 + lr;
      pa[ks] = *reinterpret_cast<const short8*>(
          (char*)P + ((i * 128 + ks * 64 + lg * 16) ^ ((i & 7) << 4)));
    }
#pragma unroll
    for (int td = 0; td < 4; ++td) {
      f32x4 o = {0.f, 0.f, 0.f, 0.f};
#pragma unroll
      for (int ks = 0; ks < 2; ++ks) {
        int dd = h * 64 + td * 16 + lr;
        short8 vb = *reinterpret_cast<const short8*>(
            (char*)vt_lds + ((dd * 128 + ks * 64 + lg * 16) ^ ((dd & 7) << 4)));
        o = mfma_b16(pa[ks], vb, o);
      }
#pragma unroll
      for (int r = 0; r < 4; ++r) {
        int token = w * 64 + ti * 16 + lg * 4 + r;
        int col = h * 64 + td * 16 + lr;
        att_out[(size_t)token * 384 + col] = f2bf(o[r]);
      }
    }
  }
}

// -------------------------------------------------------------- launch ------
extern "C" void kernel_launch(void* const* d_in, const int* in_sizes, int n_in,
                              void* d_out, int out_size, void* d_ws, size_t ws_size,
                              hipStream_t stream) {
  const float* x    = (const float*)d_in[0];
  const float* cx   = (const float*)d_in[1];
  const int*   rpi  = (const int*)d_in[2];
  const float* mask = (const float*)d_in[3];
  const float* Wq   = (const float*)d_in[4];
  const float* bq   = (const float*)d_in[5];
  const float* Wk   = (const float*)d_in[6];
  const float* bk   = (const float*)d_in[7];
  const float* Wv   = (const float*)d_in[8];
  const float* bv   = (const float*)d_in[9];
  const float* Wp   = (const float*)d_in[10];
  const float* bp   = (const float*)d_in[11];
  const float* rpb  = (const float*)d_in[12];

  char* ws = (char*)d_ws;
  unsigned short* Wq_t   = (unsigned short*)(ws + 0);        //  73,728 B
  unsigned short* Wkv_t  = (unsigned short*)(ws + 73728);    // 368,640 B
  unsigned short* Wp_t   = (unsigned short*)(ws + 442368);   // 294,912 B
  float*          bias6  = (float*)(ws + 737280);            //  98,304 B
  float*          biaskv = (float*)(ws + 835584);            //   1,920 B
  const size_t MB = 1u << 20;
  unsigned short* q_buf  = (unsigned short*)(ws + MB);                        // 25,165,824 B
  unsigned short* k_buf  = (unsigned short*)(ws + MB + 25165824u);            // 25,165,824 B
  unsigned short* vt_buf = (unsigned short*)(ws + MB + 50331648u);            // 100,663,296 B
  unsigned short* att    = (unsigned short*)(ws + MB + 150994944u);           // 100,663,296 B

  prep_k<<<256, 256, 0, stream>>>(Wq, Wk, Wv, Wp, rpb, rpi, bk, bv,
                                  Wq_t, Wkv_t, Wp_t, bias6, biaskv);
  gemm3_k<0, 0, 1><<<2048, 256, 0, stream>>>(x, Wq_t, bq, q_buf, nullptr, nullptr);
  gemm3_k<0, 2, 5><<<10240, 256, 0, stream>>>(cx, Wkv_t, biaskv, nullptr, k_buf, vt_buf);
  attn_k<<<2048, 256, 0, stream>>>(q_buf, k_buf, vt_buf, bias6, mask, att);
  gemm3_k<1, 1, 4><<<8192, 256, 0, stream>>>(att, Wp_t, bp, d_out, nullptr, nullptr);
}